// Round 1
// baseline (2907.106 us; speedup 1.0000x reference)
//
#include <hip/hip_runtime.h>
#include <cstdint>
#include <cstddef>

// ---------- types ----------
typedef float floatx4 __attribute__((ext_vector_type(4)));
typedef __bf16 bf16x8 __attribute__((ext_vector_type(8)));

__device__ __forceinline__ float bf2f(unsigned short b) {
  union { unsigned int u; float f; } a; a.u = ((unsigned int)b) << 16; return a.f;
}
__device__ __forceinline__ unsigned short f2bf(float f) {
  union { float f; unsigned int u; } a; a.f = f;
  return (unsigned short)((a.u + 0x7fffu + ((a.u >> 16) & 1u)) >> 16);
}

// async global->LDS, 16B per lane, dst = wave-uniform base + lane*16
__device__ __forceinline__ void gld_lds16(const void* g, void* l) {
  __builtin_amdgcn_global_load_lds(
      (const __attribute__((address_space(1))) unsigned int*)g,
      (__attribute__((address_space(3))) unsigned int*)l, 16, 0, 0);
}

// ---------- GEMM: C[m,n] = sum_k A[m,k] * B[n,k]  (B^T form) ----------
// A: [M,K] bf16 row-major, B: [N,K] bf16 row-major. M,N multiples of 128, K multiple of 32.
// OUT_BF16: store bf16; else fp32 (ACC: read-modify-write add).
template<int OUT_BF16, int ACC>
__global__ __launch_bounds__(256)
void k_gemm_bt(const unsigned short* __restrict__ A,
               const unsigned short* __restrict__ B,
               void* __restrict__ Cv,
               int N, int K) {
  __shared__ unsigned short sA[128 * 32];
  __shared__ unsigned short sB[128 * 32];
  const int tid  = threadIdx.x;
  const int wave = tid >> 6;
  const int lane = tid & 63;
  const int bn = blockIdx.x, bm = blockIdx.y;
  const int wr = wave >> 1, wc = wave & 1;   // 2x2 wave grid, 64x64 per wave

  floatx4 acc[4][4];
#pragma unroll
  for (int i = 0; i < 4; ++i)
#pragma unroll
    for (int j = 0; j < 4; ++j) acc[i][j] = (floatx4)(0.0f);

  // staging: wave w stages rows [w*32, w*32+32) of both tiles, 2 issues of 16 rows
  const int srow = (wave << 5) + (lane >> 2);
  const int scol = (lane & 3) << 3;
  const unsigned short* ag = A + (size_t)(bm * 128 + srow) * K + scol;
  const unsigned short* bg = B + (size_t)(bn * 128 + srow) * K + scol;
  unsigned short* lA = sA + (wave << 5) * 32;   // wave-uniform LDS base
  unsigned short* lB = sB + (wave << 5) * 32;
  const size_t rstep = (size_t)16 * K;

  // fragment LDS offsets (elements): A row = wr*64 + i*16 + (lane&15), col = (lane>>4)*8
  const int aoff = ((wr << 6) + (lane & 15)) * 32 + ((lane >> 4) << 3);
  const int boff = ((wc << 6) + (lane & 15)) * 32 + ((lane >> 4) << 3);

  for (int k0 = 0; k0 < K; k0 += 32) {
    gld_lds16(ag + k0,         lA);
    gld_lds16(ag + k0 + rstep, lA + 512);
    gld_lds16(bg + k0,         lB);
    gld_lds16(bg + k0 + rstep, lB + 512);
    __syncthreads();
    bf16x8 af[4], bf_[4];
#pragma unroll
    for (int i = 0; i < 4; ++i) af[i] = *(const bf16x8*)(sA + aoff + i * 16 * 32);
#pragma unroll
    for (int j = 0; j < 4; ++j) bf_[j] = *(const bf16x8*)(sB + boff + j * 16 * 32);
#pragma unroll
    for (int i = 0; i < 4; ++i)
#pragma unroll
      for (int j = 0; j < 4; ++j)
        acc[i][j] = __builtin_amdgcn_mfma_f32_16x16x32_bf16(af[i], bf_[j], acc[i][j], 0, 0, 0);
    __syncthreads();
  }

  // epilogue: C/D layout col=lane&15, row=(lane>>4)*4+r  [verified m89/m91]
  const int crow0 = bm * 128 + (wr << 6) + ((lane >> 4) << 2);
  const int ccol0 = bn * 128 + (wc << 6) + (lane & 15);
#pragma unroll
  for (int i = 0; i < 4; ++i)
#pragma unroll
    for (int r = 0; r < 4; ++r) {
      const size_t row = (size_t)(crow0 + i * 16 + r);
#pragma unroll
      for (int j = 0; j < 4; ++j) {
        const size_t col = (size_t)(ccol0 + j * 16);
        float v = acc[i][j][r];
        if (OUT_BF16) {
          ((unsigned short*)Cv)[row * (size_t)N + col] = f2bf(v);
        } else {
          float* C = (float*)Cv;
          if (ACC) v += C[row * (size_t)N + col];
          C[row * (size_t)N + col] = v;
        }
      }
    }
}

// ---------- elementwise kernels ----------
// fp32 -> bf16 (plain), 4 elements/thread
__global__ void k_cvt(const float* __restrict__ x, unsigned short* __restrict__ y, int n4) {
  int i = blockIdx.x * 256 + threadIdx.x;
  if (i >= n4) return;
  float4 v = ((const float4*)x)[i];
  ushort4 o;
  o.x = f2bf(v.x); o.y = f2bf(v.y); o.z = f2bf(v.z); o.w = f2bf(v.w);
  ((ushort4*)y)[i] = o;
}

// fp32 -> hi/lo bf16 split
__global__ void k_cvt_split(const float* __restrict__ x, unsigned short* __restrict__ hi,
                            unsigned short* __restrict__ lo, int n4) {
  int i = blockIdx.x * 256 + threadIdx.x;
  if (i >= n4) return;
  float4 v = ((const float4*)x)[i];
  ushort4 h, l;
  h.x = f2bf(v.x); l.x = f2bf(v.x - bf2f(h.x));
  h.y = f2bf(v.y); l.y = f2bf(v.y - bf2f(h.y));
  h.z = f2bf(v.z); l.z = f2bf(v.z - bf2f(h.z));
  h.w = f2bf(v.w); l.w = f2bf(v.w - bf2f(h.w));
  ((ushort4*)hi)[i] = h;
  ((ushort4*)lo)[i] = l;
}

// Wbig[h][0:1024]=lao[h][:]; Wbig[h][1024*(g+1)+s]=fuse[h][s][g]   (bf16)
__global__ void k_build_wbig(const float* __restrict__ lao, const float* __restrict__ fuse,
                             unsigned short* __restrict__ wbig) {
  int idx = blockIdx.x * 256 + threadIdx.x;   // over H*S = 4194304
  int h = idx >> 10, s = idx & 1023;
  size_t wb = (size_t)h * 7168;
  wbig[wb + s] = f2bf(lao[idx]);
  const float* fp = fuse + (size_t)idx * 6;
#pragma unroll
  for (int g = 0; g < 6; ++g) wbig[wb + 1024 * (g + 1) + s] = f2bf(fp[g]);
}

// T[n][1024*m + s] = ap * d^m/m! (m=0..6), orders 5,6 masked by |d|<=2.5
__global__ void k_build_T(const float* __restrict__ ap, const float* __restrict__ gp,
                          const float* __restrict__ lp, unsigned short* __restrict__ T) {
  int idx = blockIdx.x * 256 + threadIdx.x;   // over NR*S = 4194304
  int s = idx & 1023;
  float a = ap[idx];
  float d = gp[idx] - lp[s];
  size_t base = ((size_t)(idx >> 10)) * 7168 + s;
  T[base] = f2bf(a);
  float p = d;                       // d^1/1!
  T[base + 1024] = f2bf(a * p);
  p *= d * 0.5f;                     // d^2/2!
  T[base + 2048] = f2bf(a * p);
  p *= d * (1.0f / 3.0f);
  T[base + 3072] = f2bf(a * p);
  p *= d * 0.25f;
  T[base + 4096] = f2bf(a * p);
  float keep = (fabsf(d) <= 2.5f) ? 1.0f : 0.0f;
  p *= d * 0.2f;
  T[base + 5120] = f2bf(a * p * keep);
  p *= d * (1.0f / 6.0f);
  T[base + 6144] = f2bf(a * p * keep);
}

// g <- bf16( silu(g) * u ), in place, 4/thread
__global__ void k_silu_mul(unsigned short* __restrict__ g, const unsigned short* __restrict__ u, int n4) {
  int i = blockIdx.x * 256 + threadIdx.x;
  if (i >= n4) return;
  ushort4 gv = ((const ushort4*)g)[i];
  ushort4 uv = ((const ushort4*)u)[i];
  ushort4 o;
  float x;
  x = bf2f(gv.x); o.x = f2bf(x / (1.0f + expf(-x)) * bf2f(uv.x));
  x = bf2f(gv.y); o.y = f2bf(x / (1.0f + expf(-x)) * bf2f(uv.y));
  x = bf2f(gv.z); o.z = f2bf(x / (1.0f + expf(-x)) * bf2f(uv.z));
  x = bf2f(gv.w); o.w = f2bf(x / (1.0f + expf(-x)) * bf2f(uv.w));
  ((ushort4*)g)[i] = o;
}

// ---------- launch ----------
extern "C" void kernel_launch(void* const* d_in, const int* in_sizes, int n_in,
                              void* d_out, int out_size, void* d_ws, size_t ws_size,
                              hipStream_t stream) {
  const int NR = 4096, H = 4096, S = 1024, F = 9984, KB = 7168;

  const float* x    = (const float*)d_in[0];
  const float* upw  = (const float*)d_in[1];
  const float* gw   = (const float*)d_in[2];
  const float* lp   = (const float*)d_in[3];
  const float* lao  = (const float*)d_in[4];
  const float* fuse = (const float*)d_in[5];
  const float* fgw  = (const float*)d_in[7];
  const float* fuw  = (const float*)d_in[8];
  const float* fdw  = (const float*)d_in[9];
  float* out = (float*)d_out;

  char* ws = (char*)d_ws;
  unsigned short* Xhi  = (unsigned short*)(ws + 0);
  unsigned short* Xlo  = (unsigned short*)(ws + 33554432);
  unsigned short* UPb  = (unsigned short*)(ws + 67108864);
  unsigned short* GWhi = (unsigned short*)(ws + 75497472);
  unsigned short* GWlo = (unsigned short*)(ws + 83886080);
  float*          APf  = (float*)        (ws + 92274688);
  float*          GPf  = (float*)        (ws + 109051904);
  unsigned short* Wbig = (unsigned short*)(ws + 125829120);
  unsigned short* Tbig = (unsigned short*)(ws + 184549376);
  unsigned short* Wf   = (unsigned short*)(ws + 243269632);
  unsigned short* G1   = (unsigned short*)(ws + 325058560);
  unsigned short* U1   = (unsigned short*)(ws + 406847488);
  // total ws use: 488636416 bytes

  // conversions
  k_cvt_split<<<(NR * H / 4 + 255) / 256, 256, 0, stream>>>(x, Xhi, Xlo, NR * H / 4);
  k_cvt_split<<<(S * H / 4 + 255) / 256, 256, 0, stream>>>(gw, GWhi, GWlo, S * H / 4);
  k_cvt<<<(S * H / 4 + 255) / 256, 256, 0, stream>>>(upw, UPb, S * H / 4);

  // approx_up = X @ up_w^T   (fp32 out)
  k_gemm_bt<0, 0><<<dim3(S / 128, NR / 128), 256, 0, stream>>>(Xhi, UPb, (void*)APf, S, H);
  // gate_pre = X @ gate_w^T with 3-pass hi/lo split (fp32-accurate for the |d|<=2.5 mask)
  k_gemm_bt<0, 0><<<dim3(S / 128, NR / 128), 256, 0, stream>>>(Xhi, GWhi, (void*)GPf, S, H);
  k_gemm_bt<0, 1><<<dim3(S / 128, NR / 128), 256, 0, stream>>>(Xhi, GWlo, (void*)GPf, S, H);
  k_gemm_bt<0, 1><<<dim3(S / 128, NR / 128), 256, 0, stream>>>(Xlo, GWhi, (void*)GPf, S, H);

  // fused Taylor path: out = T_big @ W_big^T   (one GEMM, K = 7*1024)
  k_build_wbig<<<(H * S + 255) / 256, 256, 0, stream>>>(lao, fuse, Wbig);
  k_build_T<<<(NR * S + 255) / 256, 256, 0, stream>>>(APf, GPf, lp, Tbig);
  k_gemm_bt<0, 0><<<dim3(H / 128, NR / 128), 256, 0, stream>>>(Tbig, Wbig, (void*)out, H, KB);

  // FFN: out += (silu(X@gw^T) * (X@uw^T)) @ dw^T
  k_cvt<<<(F * H / 4 + 255) / 256, 256, 0, stream>>>(fgw, Wf, F * H / 4);
  k_gemm_bt<1, 0><<<dim3(F / 128, NR / 128), 256, 0, stream>>>(Xhi, Wf, (void*)G1, F, H);
  k_cvt<<<(F * H / 4 + 255) / 256, 256, 0, stream>>>(fuw, Wf, F * H / 4);
  k_gemm_bt<1, 0><<<dim3(F / 128, NR / 128), 256, 0, stream>>>(Xhi, Wf, (void*)U1, F, H);
  k_silu_mul<<<(NR * F / 4 + 255) / 256, 256, 0, stream>>>(G1, U1, NR * F / 4);
  k_cvt<<<(H * F / 4 + 255) / 256, 256, 0, stream>>>(fdw, Wf, H * F / 4);
  k_gemm_bt<0, 1><<<dim3(H / 128, NR / 128), 256, 0, stream>>>(G1, Wf, (void*)out, H, F);
}